// Round 1
// baseline (912.891 us; speedup 1.0000x reference)
//
#include <hip/hip_runtime.h>
#include <cstddef>

#define NN 100000
#define NE 1600000
#define IN_DIM 512
#define NEG 0.2f

// ----------------- CSR build -----------------
__global__ void k_hist(const int* __restrict__ dst, int* __restrict__ counts) {
    int i = blockIdx.x * blockDim.x + threadIdx.x;
    if (i < NE) atomicAdd(&counts[dst[i]], 1);
}

__global__ void k_scanA(const int* __restrict__ counts, int* __restrict__ indptr,
                        int* __restrict__ bsums) {
    __shared__ int sm[1024];
    int t = threadIdx.x;
    int g = blockIdx.x * 1024 + t;
    int v = (g < NN) ? counts[g] : 0;
    sm[t] = v;
    __syncthreads();
    for (int off = 1; off < 1024; off <<= 1) {
        int add = (t >= off) ? sm[t - off] : 0;
        __syncthreads();
        sm[t] += add;
        __syncthreads();
    }
    if (g < NN) indptr[g] = sm[t] - v;   // exclusive within block
    if (t == 1023) bsums[blockIdx.x] = sm[1023];
}

__global__ void k_scanB(int* __restrict__ bsums, int nb) {
    if (threadIdx.x == 0 && blockIdx.x == 0) {
        int run = 0;
        for (int i = 0; i < nb; ++i) { int c = bsums[i]; bsums[i] = run; run += c; }
    }
}

__global__ void k_scanC(int* __restrict__ indptr, const int* __restrict__ bsums) {
    int g = blockIdx.x * blockDim.x + threadIdx.x;
    if (g < NN) indptr[g] += bsums[g >> 10];
    if (g == 0) indptr[NN] = NE;
}

__global__ void k_fill(const int* __restrict__ src, const int* __restrict__ dst,
                       const int* __restrict__ indptr, int* __restrict__ cursor,
                       int* __restrict__ csr) {
    int e = blockIdx.x * blockDim.x + threadIdx.x;
    if (e < NE) {
        int d = dst[e];
        int pos = atomicAdd(&cursor[d], 1);
        csr[indptr[d] + pos] = src[e];
    }
}

// ----------------- tiled f32 matmul: out[N][64] = A[N][K] @ W[K][64] -----------------
template <int K>
__global__ __launch_bounds__(256) void k_mm(const float* __restrict__ A,
                                            const float* __restrict__ W,
                                            float* __restrict__ out) {
    __shared__ float xs[64][68];
    __shared__ float wsT[64][68];
    int tid = threadIdx.x;
    int block_row = blockIdx.x * 64;
    int tx = tid & 15, ty = tid >> 4;
    float acc[4][4] = {};
    for (int k0 = 0; k0 < K; k0 += 64) {
        #pragma unroll
        for (int i = 0; i < 4; ++i) {
            int f4 = tid + 256 * i;            // 0..1023 float4 slots
            int r = f4 >> 4, c4 = (f4 & 15) << 2;
            int row = block_row + r;
            float4 v = make_float4(0.f, 0.f, 0.f, 0.f);
            if (row < NN) v = *reinterpret_cast<const float4*>(&A[(size_t)row * K + k0 + c4]);
            *reinterpret_cast<float4*>(&xs[r][c4]) = v;
        }
        #pragma unroll
        for (int i = 0; i < 4; ++i) {
            int f4 = tid + 256 * i;
            int kk = f4 >> 4, c4 = (f4 & 15) << 2;
            float4 v = *reinterpret_cast<const float4*>(&W[(size_t)(k0 + kk) * 64 + c4]);
            wsT[c4 + 0][kk] = v.x; wsT[c4 + 1][kk] = v.y;
            wsT[c4 + 2][kk] = v.z; wsT[c4 + 3][kk] = v.w;
        }
        __syncthreads();
        #pragma unroll
        for (int k = 0; k < 64; k += 4) {
            float4 a[4], b[4];
            #pragma unroll
            for (int i = 0; i < 4; ++i) a[i] = *reinterpret_cast<const float4*>(&xs[ty * 4 + i][k]);
            #pragma unroll
            for (int j = 0; j < 4; ++j) b[j] = *reinterpret_cast<const float4*>(&wsT[tx * 4 + j][k]);
            #pragma unroll
            for (int i = 0; i < 4; ++i)
                #pragma unroll
                for (int j = 0; j < 4; ++j)
                    acc[i][j] += a[i].x * b[j].x + a[i].y * b[j].y
                               + a[i].z * b[j].z + a[i].w * b[j].w;
        }
        __syncthreads();
    }
    #pragma unroll
    for (int i = 0; i < 4; ++i) {
        int row = block_row + ty * 4 + i;
        if (row < NN) {
            float4 v = make_float4(acc[i][0], acc[i][1], acc[i][2], acc[i][3]);
            *reinterpret_cast<float4*>(&out[(size_t)row * 64 + tx * 4]) = v;
        }
    }
}

// ----------------- attention logits per node -----------------
__global__ void k_al1(const float* __restrict__ xh, const float* __restrict__ a_src,
                      const float* __restrict__ a_dst, float* __restrict__ alsrc,
                      float* __restrict__ aldst) {
    int node = blockIdx.x * 4 + (threadIdx.x >> 6);
    int lane = threadIdx.x & 63;
    if (node >= NN) return;
    float v = xh[(size_t)node * 64 + lane];
    float ps = v * a_src[lane];
    float pd = v * a_dst[lane];
    #pragma unroll
    for (int off = 1; off < 8; off <<= 1) {
        ps += __shfl_xor(ps, off, 64);
        pd += __shfl_xor(pd, off, 64);
    }
    if ((lane & 7) == 0) {
        alsrc[node * 8 + (lane >> 3)] = ps;
        aldst[node * 8 + (lane >> 3)] = pd;
    }
}

__global__ void k_al2(const float* __restrict__ xh, const float* __restrict__ a_src,
                      const float* __restrict__ a_dst, float* __restrict__ alsrc,
                      float* __restrict__ aldst) {
    int node = blockIdx.x * 4 + (threadIdx.x >> 6);
    int lane = threadIdx.x & 63;
    if (node >= NN) return;
    float v = xh[(size_t)node * 64 + lane];
    float ps = v * a_src[lane];
    float pd = v * a_dst[lane];
    #pragma unroll
    for (int off = 1; off < 64; off <<= 1) {
        ps += __shfl_xor(ps, off, 64);
        pd += __shfl_xor(pd, off, 64);
    }
    if (lane == 0) { alsrc[node] = ps; aldst[node] = pd; }
}

// ----------------- aggregation layer 1 (8 heads) + bias + relu -----------------
__global__ void k_agg1(const float* __restrict__ xh, const float* __restrict__ alsrc,
                       const float* __restrict__ aldst, const int* __restrict__ indptr,
                       const int* __restrict__ csr, const float* __restrict__ b1,
                       float* __restrict__ hout) {
    int node = blockIdx.x * 4 + (threadIdx.x >> 6);
    int lane = threadIdx.x & 63;
    if (node >= NN) return;
    int h = lane >> 3;
    float adst = aldst[node * 8 + h];
    // self loop init
    float es = alsrc[node * 8 + h] + adst;
    es = es >= 0.f ? es : NEG * es;
    float m = es, den = 1.f;
    float acc = xh[(size_t)node * 64 + lane];
    int beg = indptr[node], end = indptr[node + 1];
    for (int j = beg; j < end; ++j) {
        int s = csr[j];
        float e = alsrc[s * 8 + h] + adst;
        e = e >= 0.f ? e : NEG * e;
        float xv = xh[(size_t)s * 64 + lane];
        float nm = fmaxf(m, e);
        float sc = __expf(m - nm);
        float w = __expf(e - nm);
        den = den * sc + w;
        acc = acc * sc + w * xv;
        m = nm;
    }
    float r = acc / (den + 1e-16f) + b1[lane];
    hout[(size_t)node * 64 + lane] = fmaxf(r, 0.f);
}

// ----------------- aggregation layer 2 (1 head) + bias + log_softmax -----------------
__global__ void k_agg2(const float* __restrict__ xh, const float* __restrict__ alsrc,
                       const float* __restrict__ aldst, const int* __restrict__ indptr,
                       const int* __restrict__ csr, const float* __restrict__ b2,
                       float* __restrict__ out) {
    int node = blockIdx.x * 4 + (threadIdx.x >> 6);
    int lane = threadIdx.x & 63;
    if (node >= NN) return;
    float adst = aldst[node];
    float es = alsrc[node] + adst;
    es = es >= 0.f ? es : NEG * es;
    float m = es, den = 1.f;
    float acc = xh[(size_t)node * 64 + lane];
    int beg = indptr[node], end = indptr[node + 1];
    for (int j = beg; j < end; ++j) {
        int s = csr[j];
        float e = alsrc[s] + adst;
        e = e >= 0.f ? e : NEG * e;
        float xv = xh[(size_t)s * 64 + lane];
        float nm = fmaxf(m, e);
        float sc = __expf(m - nm);
        float w = __expf(e - nm);
        den = den * sc + w;
        acc = acc * sc + w * xv;
        m = nm;
    }
    float v = acc / (den + 1e-16f) + b2[lane];
    // log-softmax across the 64 lanes
    float mx = v;
    #pragma unroll
    for (int off = 1; off < 64; off <<= 1) mx = fmaxf(mx, __shfl_xor(mx, off, 64));
    float ex = __expf(v - mx);
    float s = ex;
    #pragma unroll
    for (int off = 1; off < 64; off <<= 1) s += __shfl_xor(s, off, 64);
    out[(size_t)node * 64 + lane] = v - mx - __logf(s);
}

// ----------------- launch -----------------
extern "C" void kernel_launch(void* const* d_in, const int* in_sizes, int n_in,
                              void* d_out, int out_size, void* d_ws, size_t ws_size,
                              hipStream_t stream) {
    const float* x   = (const float*)d_in[0];
    const int*   ei  = (const int*)d_in[1];
    const float* W1  = (const float*)d_in[2];
    const float* a1s = (const float*)d_in[3];
    const float* a1d = (const float*)d_in[4];
    const float* b1  = (const float*)d_in[5];
    const float* W2  = (const float*)d_in[6];
    const float* a2s = (const float*)d_in[7];
    const float* a2d = (const float*)d_in[8];
    const float* b2  = (const float*)d_in[9];
    float* out = (float*)d_out;
    const int* srcv = ei;
    const int* dstv = ei + NE;

    char* w = (char*)d_ws;
    auto alloc = [&](size_t bytes) {
        void* p = (void*)w;
        w += (bytes + 255) & ~(size_t)255;
        return p;
    };
    float* xh1   = (float*)alloc((size_t)NN * 64 * 4);
    float* hbuf  = (float*)alloc((size_t)NN * 64 * 4);
    float* al1s  = (float*)alloc((size_t)NN * 8 * 4);
    float* al1d  = (float*)alloc((size_t)NN * 8 * 4);
    float* al2s  = (float*)alloc((size_t)NN * 4);
    float* al2d  = (float*)alloc((size_t)NN * 4);
    int* counts  = (int*)alloc((size_t)NN * 4);
    int* cursor  = (int*)alloc((size_t)NN * 4);
    int* indptr  = (int*)alloc((size_t)(NN + 1) * 4);
    int* csr     = (int*)alloc((size_t)NE * 4);
    int* bsums   = (int*)alloc(1024 * 4);
    float* xh2   = xh1;  // reuse: xh1 dead after k_agg1

    const int nb = (NN + 1023) / 1024;  // 98

    hipMemsetAsync(counts, 0, (size_t)NN * 4, stream);
    hipMemsetAsync(cursor, 0, (size_t)NN * 4, stream);

    k_hist<<<(NE + 255) / 256, 256, 0, stream>>>(dstv, counts);
    k_scanA<<<nb, 1024, 0, stream>>>(counts, indptr, bsums);
    k_scanB<<<1, 64, 0, stream>>>(bsums, nb);
    k_scanC<<<(NN + 255) / 256, 256, 0, stream>>>(indptr, bsums);
    k_fill<<<(NE + 255) / 256, 256, 0, stream>>>(srcv, dstv, indptr, cursor, csr);

    k_mm<IN_DIM><<<(NN + 63) / 64, 256, 0, stream>>>(x, W1, xh1);
    k_al1<<<(NN + 3) / 4, 256, 0, stream>>>(xh1, a1s, a1d, al1s, al1d);
    k_agg1<<<(NN + 3) / 4, 256, 0, stream>>>(xh1, al1s, al1d, indptr, csr, b1, hbuf);

    k_mm<64><<<(NN + 63) / 64, 256, 0, stream>>>(hbuf, W2, xh2);
    k_al2<<<(NN + 3) / 4, 256, 0, stream>>>(xh2, a2s, a2d, al2s, al2d);
    k_agg2<<<(NN + 3) / 4, 256, 0, stream>>>(xh2, al2s, al2d, indptr, csr, b2, out);
}

// Round 2
// 834.594 us; speedup vs baseline: 1.0938x; 1.0938x over previous
//
#include <hip/hip_runtime.h>
#include <cstddef>

#define NN 100000
#define NE 1600000
#define IN_DIM 512
#define NEG 0.2f

// ----------------- CSR build -----------------
__global__ void k_hist(const int* __restrict__ dst, int* __restrict__ counts) {
    int i = blockIdx.x * blockDim.x + threadIdx.x;
    if (i < NE) atomicAdd(&counts[dst[i]], 1);
}

__global__ void k_scanA(const int* __restrict__ counts, int* __restrict__ indptr,
                        int* __restrict__ bsums) {
    __shared__ int sm[1024];
    int t = threadIdx.x;
    int g = blockIdx.x * 1024 + t;
    int v = (g < NN) ? counts[g] : 0;
    sm[t] = v;
    __syncthreads();
    for (int off = 1; off < 1024; off <<= 1) {
        int add = (t >= off) ? sm[t - off] : 0;
        __syncthreads();
        sm[t] += add;
        __syncthreads();
    }
    if (g < NN) indptr[g] = sm[t] - v;   // exclusive within block
    if (t == 1023) bsums[blockIdx.x] = sm[1023];
}

__global__ void k_scanB(int* __restrict__ bsums, int nb) {
    if (threadIdx.x == 0 && blockIdx.x == 0) {
        int run = 0;
        for (int i = 0; i < nb; ++i) { int c = bsums[i]; bsums[i] = run; run += c; }
    }
}

__global__ void k_scanC(int* __restrict__ indptr, const int* __restrict__ bsums) {
    int g = blockIdx.x * blockDim.x + threadIdx.x;
    if (g < NN) indptr[g] += bsums[g >> 10];
    if (g == 0) indptr[NN] = NE;
}

__global__ void k_fill(const int* __restrict__ src, const int* __restrict__ dst,
                       const int* __restrict__ indptr, int* __restrict__ cursor,
                       int* __restrict__ csr) {
    int e = blockIdx.x * blockDim.x + threadIdx.x;
    if (e < NE) {
        int d = dst[e];
        int pos = atomicAdd(&cursor[d], 1);
        csr[indptr[d] + pos] = src[e];
    }
}

// ----------------- tiled f32 matmul: out[N][64] = A[N][K] @ W[K][64] -----------------
// A staged row-major xs[row][68] (stride 68 -> 2-way on reads = free).
// W staged k-major ws[k][64] straight copy (reads: banks spread, 2-way = free).
// Inner loop: per k-quad, a[i] = 4 k's of row, b[q] = 4 cols of k+q row;
//             acc[i][j] += a[i][q] * b[q][j].
template <int K>
__global__ __launch_bounds__(256) void k_mm(const float* __restrict__ A,
                                            const float* __restrict__ W,
                                            float* __restrict__ out) {
    __shared__ float xs[64][68];
    __shared__ float ws[64][64];
    int tid = threadIdx.x;
    int block_row = blockIdx.x * 64;
    int tx = tid & 15, ty = tid >> 4;
    float acc[4][4] = {};
    for (int k0 = 0; k0 < K; k0 += 64) {
        #pragma unroll
        for (int i = 0; i < 4; ++i) {
            int f4 = tid + 256 * i;            // 0..1023 float4 slots
            int r = f4 >> 4, c4 = (f4 & 15) << 2;
            int row = block_row + r;
            float4 v = make_float4(0.f, 0.f, 0.f, 0.f);
            if (row < NN) v = *reinterpret_cast<const float4*>(&A[(size_t)row * K + k0 + c4]);
            *reinterpret_cast<float4*>(&xs[r][c4]) = v;
        }
        #pragma unroll
        for (int i = 0; i < 4; ++i) {
            int f4 = tid + 256 * i;
            int kk = f4 >> 4, c4 = (f4 & 15) << 2;
            float4 v = *reinterpret_cast<const float4*>(&W[(size_t)(k0 + kk) * 64 + c4]);
            *reinterpret_cast<float4*>(&ws[kk][c4]) = v;
        }
        __syncthreads();
        #pragma unroll
        for (int k = 0; k < 64; k += 4) {
            float4 a[4], b[4];
            #pragma unroll
            for (int i = 0; i < 4; ++i) a[i] = *reinterpret_cast<const float4*>(&xs[ty * 4 + i][k]);
            #pragma unroll
            for (int q = 0; q < 4; ++q) b[q] = *reinterpret_cast<const float4*>(&ws[k + q][tx * 4]);
            #pragma unroll
            for (int i = 0; i < 4; ++i) {
                acc[i][0] += a[i].x * b[0].x + a[i].y * b[1].x + a[i].z * b[2].x + a[i].w * b[3].x;
                acc[i][1] += a[i].x * b[0].y + a[i].y * b[1].y + a[i].z * b[2].y + a[i].w * b[3].y;
                acc[i][2] += a[i].x * b[0].z + a[i].y * b[1].z + a[i].z * b[2].z + a[i].w * b[3].z;
                acc[i][3] += a[i].x * b[0].w + a[i].y * b[1].w + a[i].z * b[2].w + a[i].w * b[3].w;
            }
        }
        __syncthreads();
    }
    #pragma unroll
    for (int i = 0; i < 4; ++i) {
        int row = block_row + ty * 4 + i;
        if (row < NN) {
            float4 v = make_float4(acc[i][0], acc[i][1], acc[i][2], acc[i][3]);
            *reinterpret_cast<float4*>(&out[(size_t)row * 64 + tx * 4]) = v;
        }
    }
}

// ----------------- attention logits per node -----------------
__global__ void k_al1(const float* __restrict__ xh, const float* __restrict__ a_src,
                      const float* __restrict__ a_dst, float* __restrict__ alsrc,
                      float* __restrict__ aldst) {
    int node = blockIdx.x * 4 + (threadIdx.x >> 6);
    int lane = threadIdx.x & 63;
    if (node >= NN) return;
    float v = xh[(size_t)node * 64 + lane];
    float ps = v * a_src[lane];
    float pd = v * a_dst[lane];
    #pragma unroll
    for (int off = 1; off < 8; off <<= 1) {
        ps += __shfl_xor(ps, off, 64);
        pd += __shfl_xor(pd, off, 64);
    }
    if ((lane & 7) == 0) {
        alsrc[node * 8 + (lane >> 3)] = ps;
        aldst[node * 8 + (lane >> 3)] = pd;
    }
}

__global__ void k_al2(const float* __restrict__ xh, const float* __restrict__ a_src,
                      const float* __restrict__ a_dst, float* __restrict__ alsrc,
                      float* __restrict__ aldst) {
    int node = blockIdx.x * 4 + (threadIdx.x >> 6);
    int lane = threadIdx.x & 63;
    if (node >= NN) return;
    float v = xh[(size_t)node * 64 + lane];
    float ps = v * a_src[lane];
    float pd = v * a_dst[lane];
    #pragma unroll
    for (int off = 1; off < 64; off <<= 1) {
        ps += __shfl_xor(ps, off, 64);
        pd += __shfl_xor(pd, off, 64);
    }
    if (lane == 0) { alsrc[node] = ps; aldst[node] = pd; }
}

// ----------------- aggregation layer 1 (8 heads) + bias + relu -----------------
__global__ void k_agg1(const float* __restrict__ xh, const float* __restrict__ alsrc,
                       const float* __restrict__ aldst, const int* __restrict__ indptr,
                       const int* __restrict__ csr, const float* __restrict__ b1,
                       float* __restrict__ hout) {
    int node = blockIdx.x * 4 + (threadIdx.x >> 6);
    int lane = threadIdx.x & 63;
    if (node >= NN) return;
    int h = lane >> 3;
    float adst = aldst[node * 8 + h];
    // self loop init
    float es = alsrc[node * 8 + h] + adst;
    es = es >= 0.f ? es : NEG * es;
    float m = es, den = 1.f;
    float acc = xh[(size_t)node * 64 + lane];
    int beg = indptr[node], end = indptr[node + 1];
    for (int j = beg; j < end; ++j) {
        int s = csr[j];
        float e = alsrc[s * 8 + h] + adst;
        e = e >= 0.f ? e : NEG * e;
        float xv = xh[(size_t)s * 64 + lane];
        float nm = fmaxf(m, e);
        float sc = __expf(m - nm);
        float w = __expf(e - nm);
        den = den * sc + w;
        acc = acc * sc + w * xv;
        m = nm;
    }
    float r = acc / (den + 1e-16f) + b1[lane];
    hout[(size_t)node * 64 + lane] = fmaxf(r, 0.f);
}

// ----------------- aggregation layer 2 (1 head) + bias + log_softmax -----------------
__global__ void k_agg2(const float* __restrict__ xh, const float* __restrict__ alsrc,
                       const float* __restrict__ aldst, const int* __restrict__ indptr,
                       const int* __restrict__ csr, const float* __restrict__ b2,
                       float* __restrict__ out) {
    int node = blockIdx.x * 4 + (threadIdx.x >> 6);
    int lane = threadIdx.x & 63;
    if (node >= NN) return;
    float adst = aldst[node];
    float es = alsrc[node] + adst;
    es = es >= 0.f ? es : NEG * es;
    float m = es, den = 1.f;
    float acc = xh[(size_t)node * 64 + lane];
    int beg = indptr[node], end = indptr[node + 1];
    for (int j = beg; j < end; ++j) {
        int s = csr[j];
        float e = alsrc[s] + adst;
        e = e >= 0.f ? e : NEG * e;
        float xv = xh[(size_t)s * 64 + lane];
        float nm = fmaxf(m, e);
        float sc = __expf(m - nm);
        float w = __expf(e - nm);
        den = den * sc + w;
        acc = acc * sc + w * xv;
        m = nm;
    }
    float v = acc / (den + 1e-16f) + b2[lane];
    // log-softmax across the 64 lanes
    float mx = v;
    #pragma unroll
    for (int off = 1; off < 64; off <<= 1) mx = fmaxf(mx, __shfl_xor(mx, off, 64));
    float ex = __expf(v - mx);
    float s = ex;
    #pragma unroll
    for (int off = 1; off < 64; off <<= 1) s += __shfl_xor(s, off, 64);
    out[(size_t)node * 64 + lane] = v - mx - __logf(s);
}

// ----------------- launch -----------------
extern "C" void kernel_launch(void* const* d_in, const int* in_sizes, int n_in,
                              void* d_out, int out_size, void* d_ws, size_t ws_size,
                              hipStream_t stream) {
    const float* x   = (const float*)d_in[0];
    const int*   ei  = (const int*)d_in[1];
    const float* W1  = (const float*)d_in[2];
    const float* a1s = (const float*)d_in[3];
    const float* a1d = (const float*)d_in[4];
    const float* b1  = (const float*)d_in[5];
    const float* W2  = (const float*)d_in[6];
    const float* a2s = (const float*)d_in[7];
    const float* a2d = (const float*)d_in[8];
    const float* b2  = (const float*)d_in[9];
    float* out = (float*)d_out;
    const int* srcv = ei;
    const int* dstv = ei + NE;

    char* w = (char*)d_ws;
    auto alloc = [&](size_t bytes) {
        void* p = (void*)w;
        w += (bytes + 255) & ~(size_t)255;
        return p;
    };
    float* xh1   = (float*)alloc((size_t)NN * 64 * 4);
    float* hbuf  = (float*)alloc((size_t)NN * 64 * 4);
    float* al1s  = (float*)alloc((size_t)NN * 8 * 4);
    float* al1d  = (float*)alloc((size_t)NN * 8 * 4);
    float* al2s  = (float*)alloc((size_t)NN * 4);
    float* al2d  = (float*)alloc((size_t)NN * 4);
    int* counts  = (int*)alloc((size_t)NN * 4);
    int* cursor  = (int*)alloc((size_t)NN * 4);
    int* indptr  = (int*)alloc((size_t)(NN + 1) * 4);
    int* csr     = (int*)alloc((size_t)NE * 4);
    int* bsums   = (int*)alloc(1024 * 4);
    float* xh2   = xh1;  // reuse: xh1 dead after k_agg1

    const int nb = (NN + 1023) / 1024;  // 98

    hipMemsetAsync(counts, 0, (size_t)NN * 4, stream);
    hipMemsetAsync(cursor, 0, (size_t)NN * 4, stream);

    k_hist<<<(NE + 255) / 256, 256, 0, stream>>>(dstv, counts);
    k_scanA<<<nb, 1024, 0, stream>>>(counts, indptr, bsums);
    k_scanB<<<1, 64, 0, stream>>>(bsums, nb);
    k_scanC<<<(NN + 255) / 256, 256, 0, stream>>>(indptr, bsums);
    k_fill<<<(NE + 255) / 256, 256, 0, stream>>>(srcv, dstv, indptr, cursor, csr);

    k_mm<IN_DIM><<<(NN + 63) / 64, 256, 0, stream>>>(x, W1, xh1);
    k_al1<<<(NN + 3) / 4, 256, 0, stream>>>(xh1, a1s, a1d, al1s, al1d);
    k_agg1<<<(NN + 3) / 4, 256, 0, stream>>>(xh1, al1s, al1d, indptr, csr, b1, hbuf);

    k_mm<64><<<(NN + 63) / 64, 256, 0, stream>>>(hbuf, W2, xh2);
    k_al2<<<(NN + 3) / 4, 256, 0, stream>>>(xh2, a2s, a2d, al2s, al2d);
    k_agg2<<<(NN + 3) / 4, 256, 0, stream>>>(xh2, al2s, al2d, indptr, csr, b2, out);
}

// Round 5
// 527.054 us; speedup vs baseline: 1.7321x; 1.5835x over previous
//
#include <hip/hip_runtime.h>
#include <cstddef>

#define NN 100000
#define NE 1600000
#define IN_DIM 512
#define NEG 0.2f

typedef short bf16x8 __attribute__((ext_vector_type(8)));
typedef float f32x4 __attribute__((ext_vector_type(4)));

__device__ __forceinline__ unsigned short f2bf_rne(float f) {
    unsigned u = __builtin_bit_cast(unsigned, f);
    unsigned r = u + 0x7fffu + ((u >> 16) & 1u);
    return (unsigned short)(r >> 16);
}
__device__ __forceinline__ float bf2f(unsigned short h) {
    unsigned u = ((unsigned)h) << 16;
    return __builtin_bit_cast(float, u);
}

// ----------------- CSR build -----------------
__global__ void k_hist(const int* __restrict__ dst, int* __restrict__ counts) {
    int i = blockIdx.x * blockDim.x + threadIdx.x;
    if (i < NE) atomicAdd(&counts[dst[i]], 1);
}

__global__ void k_scanA(const int* __restrict__ counts, int* __restrict__ indptr,
                        int* __restrict__ bsums) {
    __shared__ int sm[1024];
    int t = threadIdx.x;
    int g = blockIdx.x * 1024 + t;
    int v = (g < NN) ? counts[g] : 0;
    sm[t] = v;
    __syncthreads();
    for (int off = 1; off < 1024; off <<= 1) {
        int add = (t >= off) ? sm[t - off] : 0;
        __syncthreads();
        sm[t] += add;
        __syncthreads();
    }
    if (g < NN) indptr[g] = sm[t] - v;
    if (t == 1023) bsums[blockIdx.x] = sm[1023];
}

__global__ void k_scanB(int* __restrict__ bsums, int nb) {
    if (threadIdx.x == 0 && blockIdx.x == 0) {
        int run = 0;
        for (int i = 0; i < nb; ++i) { int c = bsums[i]; bsums[i] = run; run += c; }
    }
}

__global__ void k_scanC(int* __restrict__ indptr, const int* __restrict__ bsums) {
    int g = blockIdx.x * blockDim.x + threadIdx.x;
    if (g < NN) indptr[g] += bsums[g >> 10];
    if (g == 0) indptr[NN] = NE;
}

__global__ void k_fill(const int* __restrict__ src, const int* __restrict__ dst,
                       const int* __restrict__ indptr, int* __restrict__ cursor,
                       int* __restrict__ csr) {
    int e = blockIdx.x * blockDim.x + threadIdx.x;
    if (e < NE) {
        int d = dst[e];
        int pos = atomicAdd(&cursor[d], 1);
        csr[indptr[d] + pos] = src[e];
    }
}

// ----------------- W conversion: [K][64] f32 -> n-major bf16 hi/lo [64][K] -----------------
template <int LK>   // K = 1<<LK
__global__ void k_convW(const float* __restrict__ W, unsigned short* __restrict__ hi,
                        unsigned short* __restrict__ lo) {
    const int K = 1 << LK;
    int t = blockIdx.x * blockDim.x + threadIdx.x;
    if (t >= 64 * K) return;
    int n = t >> LK, k = t & (K - 1);
    float v = W[k * 64 + n];
    unsigned short h = f2bf_rne(v);
    hi[t] = h;
    lo[t] = f2bf_rne(v - bf2f(h));
}

// ----------------- MFMA matmul: out[N][64] = A[N][K](f32) @ W[K][64] via bf16x3 -----------
// Block = 256 thr = 4 waves; wave computes 16 rows x 64 cols with 4 n-tiles of 16x16x32.
// A-frag: lane l holds row (l&15), k = (l>>4)*8 + j  -> 8 consecutive f32 from global.
// B-frag: lane l holds col (l&15), same k's -> 16B from n-major bf16 table (L2-hot).
// C/D:    col = l&15, row = (l>>4)*4 + reg   [verified layout]
template <int K>
__global__ __launch_bounds__(256) void k_mm_mfma(const float* __restrict__ A,
                                                 const unsigned short* __restrict__ Bhi,
                                                 const unsigned short* __restrict__ Blo,
                                                 float* __restrict__ out) {
    int tid = threadIdx.x;
    int wave = tid >> 6, lane = tid & 63;
    int ln = lane & 15, kg = lane >> 4;
    int row = blockIdx.x * 64 + wave * 16 + ln;
    bool rv = row < NN;
    const float* arow = A + (size_t)row * K;
    f32x4 acc[4] = {};
    for (int k0 = 0; k0 < K; k0 += 32) {
        int ka = k0 + kg * 8;
        float4 x01 = make_float4(0.f, 0.f, 0.f, 0.f);
        float4 x23 = make_float4(0.f, 0.f, 0.f, 0.f);
        if (rv) {
            x01 = *reinterpret_cast<const float4*>(arow + ka);
            x23 = *reinterpret_cast<const float4*>(arow + ka + 4);
        }
        float xs[8] = {x01.x, x01.y, x01.z, x01.w, x23.x, x23.y, x23.z, x23.w};
        bf16x8 ah, al;
        #pragma unroll
        for (int j = 0; j < 8; ++j) {
            unsigned short h = f2bf_rne(xs[j]);
            ah[j] = (short)h;
            al[j] = (short)f2bf_rne(xs[j] - bf2f(h));
        }
        #pragma unroll
        for (int nt = 0; nt < 4; ++nt) {
            size_t off = (size_t)(nt * 16 + ln) * K + ka;
            bf16x8 bh = *reinterpret_cast<const bf16x8*>(Bhi + off);
            bf16x8 bl = *reinterpret_cast<const bf16x8*>(Blo + off);
            acc[nt] = __builtin_amdgcn_mfma_f32_16x16x32_bf16(ah, bh, acc[nt], 0, 0, 0);
            acc[nt] = __builtin_amdgcn_mfma_f32_16x16x32_bf16(al, bh, acc[nt], 0, 0, 0);
            acc[nt] = __builtin_amdgcn_mfma_f32_16x16x32_bf16(ah, bl, acc[nt], 0, 0, 0);
        }
    }
    int rbase = blockIdx.x * 64 + wave * 16 + kg * 4;
    #pragma unroll
    for (int nt = 0; nt < 4; ++nt)
        #pragma unroll
        for (int i = 0; i < 4; ++i) {
            int r = rbase + i;
            if (r < NN) out[(size_t)r * 64 + nt * 16 + ln] = acc[nt][i];
        }
}

// ----------------- attention logits per node -----------------
__global__ void k_al1(const float* __restrict__ xh, const float* __restrict__ a_src,
                      const float* __restrict__ a_dst, float* __restrict__ alsrc,
                      float* __restrict__ aldst) {
    int node = blockIdx.x * 4 + (threadIdx.x >> 6);
    int lane = threadIdx.x & 63;
    if (node >= NN) return;
    float v = xh[(size_t)node * 64 + lane];
    float ps = v * a_src[lane];
    float pd = v * a_dst[lane];
    #pragma unroll
    for (int off = 1; off < 8; off <<= 1) {
        ps += __shfl_xor(ps, off, 64);
        pd += __shfl_xor(pd, off, 64);
    }
    if ((lane & 7) == 0) {
        alsrc[node * 8 + (lane >> 3)] = ps;
        aldst[node * 8 + (lane >> 3)] = pd;
    }
}

__global__ void k_al2(const float* __restrict__ xh, const float* __restrict__ a_src,
                      const float* __restrict__ a_dst, float* __restrict__ alsrc,
                      float* __restrict__ aldst) {
    int node = blockIdx.x * 4 + (threadIdx.x >> 6);
    int lane = threadIdx.x & 63;
    if (node >= NN) return;
    float v = xh[(size_t)node * 64 + lane];
    float ps = v * a_src[lane];
    float pd = v * a_dst[lane];
    #pragma unroll
    for (int off = 1; off < 64; off <<= 1) {
        ps += __shfl_xor(ps, off, 64);
        pd += __shfl_xor(pd, off, 64);
    }
    if (lane == 0) { alsrc[node] = ps; aldst[node] = pd; }
}

// ----------------- aggregation layer 1 (8 heads) + bias + relu, unroll-4 ------------------
__global__ void k_agg1(const float* __restrict__ xh, const float* __restrict__ alsrc,
                       const float* __restrict__ aldst, const int* __restrict__ indptr,
                       const int* __restrict__ csr, const float* __restrict__ b1,
                       float* __restrict__ hout) {
    int node = blockIdx.x * 4 + (threadIdx.x >> 6);
    int lane = threadIdx.x & 63;
    if (node >= NN) return;
    int h = lane >> 3;
    float adst = aldst[node * 8 + h];
    float es = alsrc[node * 8 + h] + adst;
    es = es >= 0.f ? es : NEG * es;
    float m = es, den = 1.f;
    float acc = xh[(size_t)node * 64 + lane];
    int beg = indptr[node], end = indptr[node + 1];
    int j = beg;
    for (; j + 3 < end; j += 4) {
        int s0 = csr[j], s1 = csr[j + 1], s2 = csr[j + 2], s3 = csr[j + 3];
        float e0 = alsrc[s0 * 8 + h] + adst;
        float e1 = alsrc[s1 * 8 + h] + adst;
        float e2 = alsrc[s2 * 8 + h] + adst;
        float e3 = alsrc[s3 * 8 + h] + adst;
        e0 = e0 >= 0.f ? e0 : NEG * e0;
        e1 = e1 >= 0.f ? e1 : NEG * e1;
        e2 = e2 >= 0.f ? e2 : NEG * e2;
        e3 = e3 >= 0.f ? e3 : NEG * e3;
        float v0 = xh[(size_t)s0 * 64 + lane];
        float v1 = xh[(size_t)s1 * 64 + lane];
        float v2 = xh[(size_t)s2 * 64 + lane];
        float v3 = xh[(size_t)s3 * 64 + lane];
        float nm = fmaxf(fmaxf(fmaxf(e0, e1), fmaxf(e2, e3)), m);
        float sc = __expf(m - nm);
        float w0 = __expf(e0 - nm), w1 = __expf(e1 - nm);
        float w2 = __expf(e2 - nm), w3 = __expf(e3 - nm);
        den = den * sc + (w0 + w1) + (w2 + w3);
        acc = acc * sc + (w0 * v0 + w1 * v1) + (w2 * v2 + w3 * v3);
        m = nm;
    }
    for (; j < end; ++j) {
        int s = csr[j];
        float e = alsrc[s * 8 + h] + adst;
        e = e >= 0.f ? e : NEG * e;
        float xv = xh[(size_t)s * 64 + lane];
        float nm = fmaxf(m, e);
        float sc = __expf(m - nm);
        float w = __expf(e - nm);
        den = den * sc + w;
        acc = acc * sc + w * xv;
        m = nm;
    }
    float r = acc / (den + 1e-16f) + b1[lane];
    hout[(size_t)node * 64 + lane] = fmaxf(r, 0.f);
}

// ----------------- aggregation layer 2 (1 head) + bias + log_softmax, unroll-4 ------------
__global__ void k_agg2(const float* __restrict__ xh, const float* __restrict__ alsrc,
                       const float* __restrict__ aldst, const int* __restrict__ indptr,
                       const int* __restrict__ csr, const float* __restrict__ b2,
                       float* __restrict__ out) {
    int node = blockIdx.x * 4 + (threadIdx.x >> 6);
    int lane = threadIdx.x & 63;
    if (node >= NN) return;
    float adst = aldst[node];
    float es = alsrc[node] + adst;
    es = es >= 0.f ? es : NEG * es;
    float m = es, den = 1.f;
    float acc = xh[(size_t)node * 64 + lane];
    int beg = indptr[node], end = indptr[node + 1];
    int j = beg;
    for (; j + 3 < end; j += 4) {
        int s0 = csr[j], s1 = csr[j + 1], s2 = csr[j + 2], s3 = csr[j + 3];
        float e0 = alsrc[s0] + adst;
        float e1 = alsrc[s1] + adst;
        float e2 = alsrc[s2] + adst;
        float e3 = alsrc[s3] + adst;
        e0 = e0 >= 0.f ? e0 : NEG * e0;
        e1 = e1 >= 0.f ? e1 : NEG * e1;
        e2 = e2 >= 0.f ? e2 : NEG * e2;
        e3 = e3 >= 0.f ? e3 : NEG * e3;
        float v0 = xh[(size_t)s0 * 64 + lane];
        float v1 = xh[(size_t)s1 * 64 + lane];
        float v2 = xh[(size_t)s2 * 64 + lane];
        float v3 = xh[(size_t)s3 * 64 + lane];
        float nm = fmaxf(fmaxf(fmaxf(e0, e1), fmaxf(e2, e3)), m);
        float sc = __expf(m - nm);
        float w0 = __expf(e0 - nm), w1 = __expf(e1 - nm);
        float w2 = __expf(e2 - nm), w3 = __expf(e3 - nm);
        den = den * sc + (w0 + w1) + (w2 + w3);
        acc = acc * sc + (w0 * v0 + w1 * v1) + (w2 * v2 + w3 * v3);
        m = nm;
    }
    for (; j < end; ++j) {
        int s = csr[j];
        float e = alsrc[s] + adst;
        e = e >= 0.f ? e : NEG * e;
        float xv = xh[(size_t)s * 64 + lane];
        float nm = fmaxf(m, e);
        float sc = __expf(m - nm);
        float w = __expf(e - nm);
        den = den * sc + w;
        acc = acc * sc + w * xv;
        m = nm;
    }
    float v = acc / (den + 1e-16f) + b2[lane];
    float mx = v;
    #pragma unroll
    for (int off = 1; off < 64; off <<= 1) mx = fmaxf(mx, __shfl_xor(mx, off, 64));
    float ex = __expf(v - mx);
    float s = ex;
    #pragma unroll
    for (int off = 1; off < 64; off <<= 1) s += __shfl_xor(s, off, 64);
    out[(size_t)node * 64 + lane] = v - mx - __logf(s);
}

// ----------------- launch -----------------
extern "C" void kernel_launch(void* const* d_in, const int* in_sizes, int n_in,
                              void* d_out, int out_size, void* d_ws, size_t ws_size,
                              hipStream_t stream) {
    const float* x   = (const float*)d_in[0];
    const int*   ei  = (const int*)d_in[1];
    const float* W1  = (const float*)d_in[2];
    const float* a1s = (const float*)d_in[3];
    const float* a1d = (const float*)d_in[4];
    const float* b1  = (const float*)d_in[5];
    const float* W2  = (const float*)d_in[6];
    const float* a2s = (const float*)d_in[7];
    const float* a2d = (const float*)d_in[8];
    const float* b2  = (const float*)d_in[9];
    float* out = (float*)d_out;
    const int* srcv = ei;
    const int* dstv = ei + NE;

    char* w = (char*)d_ws;
    auto alloc = [&](size_t bytes) {
        void* p = (void*)w;
        w += (bytes + 255) & ~(size_t)255;
        return p;
    };
    float* xh1   = (float*)alloc((size_t)NN * 64 * 4);
    float* hbuf  = (float*)alloc((size_t)NN * 64 * 4);
    float* al1s  = (float*)alloc((size_t)NN * 8 * 4);
    float* al1d  = (float*)alloc((size_t)NN * 8 * 4);
    float* al2s  = (float*)alloc((size_t)NN * 4);
    float* al2d  = (float*)alloc((size_t)NN * 4);
    int* counts  = (int*)alloc((size_t)NN * 4);
    int* cursor  = (int*)alloc((size_t)NN * 4);
    int* indptr  = (int*)alloc((size_t)(NN + 1) * 4);
    int* csr     = (int*)alloc((size_t)NE * 4);
    int* bsums   = (int*)alloc(1024 * 4);
    unsigned short* Wb1h = (unsigned short*)alloc((size_t)64 * IN_DIM * 2);
    unsigned short* Wb1l = (unsigned short*)alloc((size_t)64 * IN_DIM * 2);
    unsigned short* Wb2h = (unsigned short*)alloc((size_t)64 * 64 * 2);
    unsigned short* Wb2l = (unsigned short*)alloc((size_t)64 * 64 * 2);
    float* xh2   = xh1;  // reuse: xh1 dead after k_agg1

    const int nb = (NN + 1023) / 1024;  // 98

    hipMemsetAsync(counts, 0, (size_t)NN * 4, stream);
    hipMemsetAsync(cursor, 0, (size_t)NN * 4, stream);

    k_convW<9><<<(64 * IN_DIM + 255) / 256, 256, 0, stream>>>(W1, Wb1h, Wb1l);
    k_convW<6><<<(64 * 64 + 255) / 256, 256, 0, stream>>>(W2, Wb2h, Wb2l);

    k_hist<<<(NE + 255) / 256, 256, 0, stream>>>(dstv, counts);
    k_scanA<<<nb, 1024, 0, stream>>>(counts, indptr, bsums);
    k_scanB<<<1, 64, 0, stream>>>(bsums, nb);
    k_scanC<<<(NN + 255) / 256, 256, 0, stream>>>(indptr, bsums);
    k_fill<<<(NE + 255) / 256, 256, 0, stream>>>(srcv, dstv, indptr, cursor, csr);

    k_mm_mfma<IN_DIM><<<(NN + 63) / 64, 256, 0, stream>>>(x, Wb1h, Wb1l, xh1);
    k_al1<<<(NN + 3) / 4, 256, 0, stream>>>(xh1, a1s, a1d, al1s, al1d);
    k_agg1<<<(NN + 3) / 4, 256, 0, stream>>>(xh1, al1s, al1d, indptr, csr, b1, hbuf);

    k_mm_mfma<64><<<(NN + 63) / 64, 256, 0, stream>>>(hbuf, Wb2h, Wb2l, xh2);
    k_al2<<<(NN + 3) / 4, 256, 0, stream>>>(xh2, a2s, a2d, al2s, al2d);
    k_agg2<<<(NN + 3) / 4, 256, 0, stream>>>(xh2, al2s, al2d, indptr, csr, b2, out);
}

// Round 6
// 512.276 us; speedup vs baseline: 1.7820x; 1.0288x over previous
//
#include <hip/hip_runtime.h>
#include <cstddef>

#define NN 100000
#define NE 1600000
#define IN_DIM 512
#define NEG 0.2f

typedef short bf16x8 __attribute__((ext_vector_type(8)));
typedef float f32x4 __attribute__((ext_vector_type(4)));

__device__ __forceinline__ unsigned short f2bf_rne(float f) {
    unsigned u = __builtin_bit_cast(unsigned, f);
    unsigned r = u + 0x7fffu + ((u >> 16) & 1u);
    return (unsigned short)(r >> 16);
}
__device__ __forceinline__ float bf2f(unsigned short h) {
    unsigned u = ((unsigned)h) << 16;
    return __builtin_bit_cast(float, u);
}

// ----------------- CSR build -----------------
__global__ void k_hist(const int* __restrict__ dst, int* __restrict__ counts) {
    int i = blockIdx.x * blockDim.x + threadIdx.x;
    if (i < NE) atomicAdd(&counts[dst[i]], 1);
}

__global__ void k_scanA(const int* __restrict__ counts, int* __restrict__ indptr,
                        int* __restrict__ bsums) {
    __shared__ int sm[1024];
    int t = threadIdx.x;
    int g = blockIdx.x * 1024 + t;
    int v = (g < NN) ? counts[g] : 0;
    sm[t] = v;
    __syncthreads();
    for (int off = 1; off < 1024; off <<= 1) {
        int add = (t >= off) ? sm[t - off] : 0;
        __syncthreads();
        sm[t] += add;
        __syncthreads();
    }
    if (g < NN) indptr[g] = sm[t] - v;
    if (t == 1023) bsums[blockIdx.x] = sm[1023];
}

__global__ void k_scanB(int* __restrict__ bsums, int nb) {
    if (threadIdx.x == 0 && blockIdx.x == 0) {
        int run = 0;
        for (int i = 0; i < nb; ++i) { int c = bsums[i]; bsums[i] = run; run += c; }
    }
}

__global__ void k_scanC(int* __restrict__ indptr, const int* __restrict__ bsums) {
    int g = blockIdx.x * blockDim.x + threadIdx.x;
    if (g < NN) indptr[g] += bsums[g >> 10];
    if (g == 0) indptr[NN] = NE;
}

__global__ void k_fill(const int* __restrict__ src, const int* __restrict__ dst,
                       const int* __restrict__ indptr, int* __restrict__ cursor,
                       int* __restrict__ csr) {
    int e = blockIdx.x * blockDim.x + threadIdx.x;
    if (e < NE) {
        int d = dst[e];
        int pos = atomicAdd(&cursor[d], 1);
        csr[indptr[d] + pos] = src[e];
    }
}

// ----------------- W conversion: [K][64] f32 -> n-major bf16 hi/lo [64][K] -----------------
template <int LK>   // K = 1<<LK
__global__ void k_convW(const float* __restrict__ W, unsigned short* __restrict__ hi,
                        unsigned short* __restrict__ lo) {
    const int K = 1 << LK;
    int t = blockIdx.x * blockDim.x + threadIdx.x;
    if (t >= 64 * K) return;
    int n = t >> LK, k = t & (K - 1);
    float v = W[k * 64 + n];
    unsigned short h = f2bf_rne(v);
    hi[t] = h;
    lo[t] = f2bf_rne(v - bf2f(h));
}

// ----------------- MFMA matmul: out[N][64] = A[N][K](f32) @ W[K][64] via bf16x3 -----------
// Depth-2 software pipeline on the A-stream (latency-bound fix, R5 post-mortem).
template <int K>
__global__ __launch_bounds__(256) void k_mm_mfma(const float* __restrict__ A,
                                                 const unsigned short* __restrict__ Bhi,
                                                 const unsigned short* __restrict__ Blo,
                                                 float* __restrict__ out) {
    const int NIT = K / 32;
    int tid = threadIdx.x;
    int wave = tid >> 6, lane = tid & 63;
    int ln = lane & 15, kg = lane >> 4;
    int row = blockIdx.x * 64 + wave * 16 + ln;
    bool rv = row < NN;
    const float* arow = A + (size_t)row * K;
    f32x4 acc[4] = {};
    float4 z = make_float4(0.f, 0.f, 0.f, 0.f);
    float4 p0a = z, p0b = z, p1a = z, p1b = z;
    if (rv) {
        p0a = *reinterpret_cast<const float4*>(arow + kg * 8);
        p0b = *reinterpret_cast<const float4*>(arow + kg * 8 + 4);
        if (NIT > 1) {
            p1a = *reinterpret_cast<const float4*>(arow + 32 + kg * 8);
            p1b = *reinterpret_cast<const float4*>(arow + 32 + kg * 8 + 4);
        }
    }
    for (int it = 0; it < NIT; ++it) {
        float4 x01 = p0a, x23 = p0b;
        p0a = p1a; p0b = p1b;
        if (it + 2 < NIT && rv) {
            int kn = (it + 2) * 32 + kg * 8;
            p1a = *reinterpret_cast<const float4*>(arow + kn);
            p1b = *reinterpret_cast<const float4*>(arow + kn + 4);
        }
        int ka = it * 32 + kg * 8;
        float xs[8] = {x01.x, x01.y, x01.z, x01.w, x23.x, x23.y, x23.z, x23.w};
        bf16x8 ah, al;
        #pragma unroll
        for (int j = 0; j < 8; ++j) {
            unsigned short h = f2bf_rne(xs[j]);
            ah[j] = (short)h;
            al[j] = (short)f2bf_rne(xs[j] - bf2f(h));
        }
        #pragma unroll
        for (int nt = 0; nt < 4; ++nt) {
            size_t off = (size_t)(nt * 16 + ln) * K + ka;
            bf16x8 bh = *reinterpret_cast<const bf16x8*>(Bhi + off);
            bf16x8 bl = *reinterpret_cast<const bf16x8*>(Blo + off);
            acc[nt] = __builtin_amdgcn_mfma_f32_16x16x32_bf16(ah, bh, acc[nt], 0, 0, 0);
            acc[nt] = __builtin_amdgcn_mfma_f32_16x16x32_bf16(al, bh, acc[nt], 0, 0, 0);
            acc[nt] = __builtin_amdgcn_mfma_f32_16x16x32_bf16(ah, bl, acc[nt], 0, 0, 0);
        }
    }
    int rbase = blockIdx.x * 64 + wave * 16 + kg * 4;
    #pragma unroll
    for (int nt = 0; nt < 4; ++nt)
        #pragma unroll
        for (int i = 0; i < 4; ++i) {
            int r = rbase + i;
            if (r < NN) out[(size_t)r * 64 + nt * 16 + ln] = acc[nt][i];
        }
}

// ----------------- attention logits per node -----------------
__global__ void k_al1(const float* __restrict__ xh, const float* __restrict__ a_src,
                      const float* __restrict__ a_dst, float* __restrict__ alsrc,
                      float* __restrict__ aldst) {
    int node = blockIdx.x * 4 + (threadIdx.x >> 6);
    int lane = threadIdx.x & 63;
    if (node >= NN) return;
    float v = xh[(size_t)node * 64 + lane];
    float ps = v * a_src[lane];
    float pd = v * a_dst[lane];
    #pragma unroll
    for (int off = 1; off < 8; off <<= 1) {
        ps += __shfl_xor(ps, off, 64);
        pd += __shfl_xor(pd, off, 64);
    }
    if ((lane & 7) == 0) {
        alsrc[node * 8 + (lane >> 3)] = ps;
        aldst[node * 8 + (lane >> 3)] = pd;
    }
}

__global__ void k_al2(const float* __restrict__ xh, const float* __restrict__ a_src,
                      const float* __restrict__ a_dst, float* __restrict__ alsrc,
                      float* __restrict__ aldst) {
    int node = blockIdx.x * 4 + (threadIdx.x >> 6);
    int lane = threadIdx.x & 63;
    if (node >= NN) return;
    float v = xh[(size_t)node * 64 + lane];
    float ps = v * a_src[lane];
    float pd = v * a_dst[lane];
    #pragma unroll
    for (int off = 1; off < 64; off <<= 1) {
        ps += __shfl_xor(ps, off, 64);
        pd += __shfl_xor(pd, off, 64);
    }
    if (lane == 0) { alsrc[node] = ps; aldst[node] = pd; }
}

// ----------------- aggregation layer 1: dual-state online softmax, 8 edges in flight ------
__global__ void k_agg1(const float* __restrict__ xh, const float* __restrict__ alsrc,
                       const float* __restrict__ aldst, const int* __restrict__ indptr,
                       const int* __restrict__ csr, const float* __restrict__ b1,
                       float* __restrict__ hout) {
    int node = blockIdx.x * 4 + (threadIdx.x >> 6);
    int lane = threadIdx.x & 63;
    if (node >= NN) return;
    int h = lane >> 3;
    float adst = aldst[node * 8 + h];
    float es = alsrc[node * 8 + h] + adst;
    es = es >= 0.f ? es : NEG * es;
    // state A (self-loop init), state B (empty)
    float mA = es, dA = 1.f, aA = xh[(size_t)node * 64 + lane];
    float mB = -3e38f, dB = 0.f, aB = 0.f;
    int beg = indptr[node], end = indptr[node + 1];
    int j = beg;

    auto upd4 = [&](int s0, int s1, int s2, int s3, float& m, float& d, float& a) {
        float e0 = alsrc[s0 * 8 + h] + adst;
        float e1 = alsrc[s1 * 8 + h] + adst;
        float e2 = alsrc[s2 * 8 + h] + adst;
        float e3 = alsrc[s3 * 8 + h] + adst;
        e0 = e0 >= 0.f ? e0 : NEG * e0;
        e1 = e1 >= 0.f ? e1 : NEG * e1;
        e2 = e2 >= 0.f ? e2 : NEG * e2;
        e3 = e3 >= 0.f ? e3 : NEG * e3;
        float v0 = xh[(size_t)s0 * 64 + lane];
        float v1 = xh[(size_t)s1 * 64 + lane];
        float v2 = xh[(size_t)s2 * 64 + lane];
        float v3 = xh[(size_t)s3 * 64 + lane];
        float nm = fmaxf(fmaxf(fmaxf(e0, e1), fmaxf(e2, e3)), m);
        float sc = __expf(m - nm);
        float w0 = __expf(e0 - nm), w1 = __expf(e1 - nm);
        float w2 = __expf(e2 - nm), w3 = __expf(e3 - nm);
        d = d * sc + (w0 + w1) + (w2 + w3);
        a = a * sc + (w0 * v0 + w1 * v1) + (w2 * v2 + w3 * v3);
        m = nm;
    };

    for (; j + 7 < end; j += 8) {
        int s0 = csr[j],     s1 = csr[j + 1], s2 = csr[j + 2], s3 = csr[j + 3];
        int s4 = csr[j + 4], s5 = csr[j + 5], s6 = csr[j + 6], s7 = csr[j + 7];
        upd4(s0, s1, s2, s3, mA, dA, aA);
        upd4(s4, s5, s6, s7, mB, dB, aB);
    }
    for (; j + 3 < end; j += 4)
        upd4(csr[j], csr[j + 1], csr[j + 2], csr[j + 3], mA, dA, aA);
    for (; j < end; ++j) {
        int s = csr[j];
        float e = alsrc[s * 8 + h] + adst;
        e = e >= 0.f ? e : NEG * e;
        float xv = xh[(size_t)s * 64 + lane];
        float nm = fmaxf(mA, e);
        float sc = __expf(mA - nm);
        float w = __expf(e - nm);
        dA = dA * sc + w;
        aA = aA * sc + w * xv;
        mA = nm;
    }
    // merge B into A
    {
        float nm = fmaxf(mA, mB);
        float sA = __expf(mA - nm), sB = __expf(mB - nm);
        dA = dA * sA + dB * sB;
        aA = aA * sA + aB * sB;
    }
    float r = aA / (dA + 1e-16f) + b1[lane];
    hout[(size_t)node * 64 + lane] = fmaxf(r, 0.f);
}

// ----------------- aggregation layer 2: dual-state + log_softmax ------
__global__ void k_agg2(const float* __restrict__ xh, const float* __restrict__ alsrc,
                       const float* __restrict__ aldst, const int* __restrict__ indptr,
                       const int* __restrict__ csr, const float* __restrict__ b2,
                       float* __restrict__ out) {
    int node = blockIdx.x * 4 + (threadIdx.x >> 6);
    int lane = threadIdx.x & 63;
    if (node >= NN) return;
    float adst = aldst[node];
    float es = alsrc[node] + adst;
    es = es >= 0.f ? es : NEG * es;
    float mA = es, dA = 1.f, aA = xh[(size_t)node * 64 + lane];
    float mB = -3e38f, dB = 0.f, aB = 0.f;
    int beg = indptr[node], end = indptr[node + 1];
    int j = beg;

    auto upd4 = [&](int s0, int s1, int s2, int s3, float& m, float& d, float& a) {
        float e0 = alsrc[s0] + adst;
        float e1 = alsrc[s1] + adst;
        float e2 = alsrc[s2] + adst;
        float e3 = alsrc[s3] + adst;
        e0 = e0 >= 0.f ? e0 : NEG * e0;
        e1 = e1 >= 0.f ? e1 : NEG * e1;
        e2 = e2 >= 0.f ? e2 : NEG * e2;
        e3 = e3 >= 0.f ? e3 : NEG * e3;
        float v0 = xh[(size_t)s0 * 64 + lane];
        float v1 = xh[(size_t)s1 * 64 + lane];
        float v2 = xh[(size_t)s2 * 64 + lane];
        float v3 = xh[(size_t)s3 * 64 + lane];
        float nm = fmaxf(fmaxf(fmaxf(e0, e1), fmaxf(e2, e3)), m);
        float sc = __expf(m - nm);
        float w0 = __expf(e0 - nm), w1 = __expf(e1 - nm);
        float w2 = __expf(e2 - nm), w3 = __expf(e3 - nm);
        d = d * sc + (w0 + w1) + (w2 + w3);
        a = a * sc + (w0 * v0 + w1 * v1) + (w2 * v2 + w3 * v3);
        m = nm;
    };

    for (; j + 7 < end; j += 8) {
        int s0 = csr[j],     s1 = csr[j + 1], s2 = csr[j + 2], s3 = csr[j + 3];
        int s4 = csr[j + 4], s5 = csr[j + 5], s6 = csr[j + 6], s7 = csr[j + 7];
        upd4(s0, s1, s2, s3, mA, dA, aA);
        upd4(s4, s5, s6, s7, mB, dB, aB);
    }
    for (; j + 3 < end; j += 4)
        upd4(csr[j], csr[j + 1], csr[j + 2], csr[j + 3], mA, dA, aA);
    for (; j < end; ++j) {
        int s = csr[j];
        float e = alsrc[s] + adst;
        e = e >= 0.f ? e : NEG * e;
        float xv = xh[(size_t)s * 64 + lane];
        float nm = fmaxf(mA, e);
        float sc = __expf(mA - nm);
        float w = __expf(e - nm);
        dA = dA * sc + w;
        aA = aA * sc + w * xv;
        mA = nm;
    }
    {
        float nm = fmaxf(mA, mB);
        float sA = __expf(mA - nm), sB = __expf(mB - nm);
        dA = dA * sA + dB * sB;
        aA = aA * sA + aB * sB;
    }
    float v = aA / (dA + 1e-16f) + b2[lane];
    float mx = v;
    #pragma unroll
    for (int off = 1; off < 64; off <<= 1) mx = fmaxf(mx, __shfl_xor(mx, off, 64));
    float ex = __expf(v - mx);
    float s = ex;
    #pragma unroll
    for (int off = 1; off < 64; off <<= 1) s += __shfl_xor(s, off, 64);
    out[(size_t)node * 64 + lane] = v - mx - __logf(s);
}

// ----------------- launch -----------------
extern "C" void kernel_launch(void* const* d_in, const int* in_sizes, int n_in,
                              void* d_out, int out_size, void* d_ws, size_t ws_size,
                              hipStream_t stream) {
    const float* x   = (const float*)d_in[0];
    const int*   ei  = (const int*)d_in[1];
    const float* W1  = (const float*)d_in[2];
    const float* a1s = (const float*)d_in[3];
    const float* a1d = (const float*)d_in[4];
    const float* b1  = (const float*)d_in[5];
    const float* W2  = (const float*)d_in[6];
    const float* a2s = (const float*)d_in[7];
    const float* a2d = (const float*)d_in[8];
    const float* b2  = (const float*)d_in[9];
    float* out = (float*)d_out;
    const int* srcv = ei;
    const int* dstv = ei + NE;

    char* w = (char*)d_ws;
    auto alloc = [&](size_t bytes) {
        void* p = (void*)w;
        w += (bytes + 255) & ~(size_t)255;
        return p;
    };
    float* xh1   = (float*)alloc((size_t)NN * 64 * 4);
    float* hbuf  = (float*)alloc((size_t)NN * 64 * 4);
    float* al1s  = (float*)alloc((size_t)NN * 8 * 4);
    float* al1d  = (float*)alloc((size_t)NN * 8 * 4);
    float* al2s  = (float*)alloc((size_t)NN * 4);
    float* al2d  = (float*)alloc((size_t)NN * 4);
    int* counts  = (int*)alloc((size_t)NN * 4);
    int* cursor  = (int*)alloc((size_t)NN * 4);
    int* indptr  = (int*)alloc((size_t)(NN + 1) * 4);
    int* csr     = (int*)alloc((size_t)NE * 4);
    int* bsums   = (int*)alloc(1024 * 4);
    unsigned short* Wb1h = (unsigned short*)alloc((size_t)64 * IN_DIM * 2);
    unsigned short* Wb1l = (unsigned short*)alloc((size_t)64 * IN_DIM * 2);
    unsigned short* Wb2h = (unsigned short*)alloc((size_t)64 * 64 * 2);
    unsigned short* Wb2l = (unsigned short*)alloc((size_t)64 * 64 * 2);
    float* xh2   = xh1;  // reuse: xh1 dead after k_agg1

    const int nb = (NN + 1023) / 1024;  // 98

    hipMemsetAsync(counts, 0, (size_t)NN * 4, stream);
    hipMemsetAsync(cursor, 0, (size_t)NN * 4, stream);

    k_convW<9><<<(64 * IN_DIM + 255) / 256, 256, 0, stream>>>(W1, Wb1h, Wb1l);
    k_convW<6><<<(64 * 64 + 255) / 256, 256, 0, stream>>>(W2, Wb2h, Wb2l);

    k_hist<<<(NE + 255) / 256, 256, 0, stream>>>(dstv, counts);
    k_scanA<<<nb, 1024, 0, stream>>>(counts, indptr, bsums);
    k_scanB<<<1, 64, 0, stream>>>(bsums, nb);
    k_scanC<<<(NN + 255) / 256, 256, 0, stream>>>(indptr, bsums);
    k_fill<<<(NE + 255) / 256, 256, 0, stream>>>(srcv, dstv, indptr, cursor, csr);

    k_mm_mfma<IN_DIM><<<(NN + 63) / 64, 256, 0, stream>>>(x, Wb1h, Wb1l, xh1);
    k_al1<<<(NN + 3) / 4, 256, 0, stream>>>(xh1, a1s, a1d, al1s, al1d);
    k_agg1<<<(NN + 3) / 4, 256, 0, stream>>>(xh1, al1s, al1d, indptr, csr, b1, hbuf);

    k_mm_mfma<64><<<(NN + 63) / 64, 256, 0, stream>>>(hbuf, Wb2h, Wb2l, xh2);
    k_al2<<<(NN + 3) / 4, 256, 0, stream>>>(xh2, a2s, a2d, al2s, al2d);
    k_agg2<<<(NN + 3) / 4, 256, 0, stream>>>(xh2, al2s, al2d, indptr, csr, b2, out);
}